// Round 7
// baseline (114.262 us; speedup 1.0000x reference)
//
#include <hip/hip_runtime.h>
#include <math.h>

// ---------------------------------------------------------------------------
// Difflogic network, collapsed form:
//   per neuron: out = c0 + c1*p + c2*q + c3*p*q,  p = A·x, q = B·x
//   A,B = softmax(sel), (c0..c3) = softmax(gate_logits) · gate-coef table
//
// R14 -> R15: shrink VMEM instruction stream + protect L2.
//  - 18 floats/thread loaded as 4x dwordx4 + 1x dwordx2 (5 VMEM insts vs 9);
//    line-touches scale with instruction count at this stride (~64/instr)
//    -> ~35% fewer TA cycles.  8B alignment is legal for dwordx4 (multi-dword
//    global loads need only dword alignment on CDNA); ext_vector aligned(8).
//  - Nontemporal loads on x (read-once; keeps the hot 1.2KB cf lines in L2,
//    which every one of 8192 waves re-s_loads) and NT store on out.
//  - Otherwise identical to R14 (SPT=2 packed v_pk_fma_f32 body, zero LDS,
//    cf via uniform s_load -> SGPR operands, launch_bounds(256,8)).
// Fusion re-examined and re-rejected: fused cf would move ~84 b128-class LDS
// reads/thread onto the per-CU LDS pipe (4-8us) to save ~2-3us of dispatch.
// Pre-commit: if |delta| <= 1.5us, controllable budget is exhausted
// (86us harness fills + ~1.5 coeff + ~10-12 steady net + ~5 first-iter
// amortization) -> declare roofline next round.
//
// ws layout (floats):
//   A1:   0 (72)   B1:  72 (72)   C1: 144 (32)
//   A2: 176 (32)   B2: 208 (32)   C2: 240 (16)
//   A3: 256 ( 8)   B3: 264 ( 8)   C3: 272 ( 8)
//   A4: 280 ( 2)   B4: 282 ( 2)   C4: 284 ( 4)   total 288 floats = 1152 B
// ---------------------------------------------------------------------------

#define THREADS 256
#define SPT 2                              // samples per thread (packed)
#define B_PER_BLOCK (THREADS * SPT)        // 512 samples

typedef float v2f __attribute__((ext_vector_type(2)));
typedef float v4f __attribute__((ext_vector_type(4), aligned(8)));  // 8B-aligned ok

static __device__ __forceinline__ v2f sp(float s) { v2f r; r.x = s; r.y = s; return r; }
static __device__ __forceinline__ v2f pfma(v2f a, v2f b, v2f c) {
    return __builtin_elementwise_fma(a, b, c);
}

template <int D>
__device__ __forceinline__ void softmax_row(const float* __restrict__ src,
                                            float* __restrict__ dst) {
    float e[D];
    float m = src[0];
    #pragma unroll
    for (int i = 1; i < D; ++i) m = fmaxf(m, src[i]);
    float s = 0.f;
    #pragma unroll
    for (int i = 0; i < D; ++i) { e[i] = __expf(src[i] - m); s += e[i]; }
    float inv = 1.f / s;
    #pragma unroll
    for (int i = 0; i < D; ++i) dst[i] = e[i] * inv;
}

__device__ __forceinline__ void gate_fold(const float* __restrict__ g,
                                          float* __restrict__ C) {
    const float k0[16]  = {0,0,0,0, 0,0,0,0, 1, 1, 1, 1, 1, 1, 1, 1};
    const float kp[16]  = {0,0,1,1, 0,0,1,1,-1,-1, 0, 0,-1,-1, 0, 0};
    const float kq[16]  = {0,0,0,0, 1,1,1,1,-1,-1,-1,-1, 0, 0, 0, 0};
    const float kpq[16] = {0,1,-1,0,-1,0,-2,-1, 1, 2, 0, 1, 0, 1,-1, 0};
    float w[16];
    float m = g[0];
    #pragma unroll
    for (int i = 1; i < 16; ++i) m = fmaxf(m, g[i]);
    float s = 0.f;
    #pragma unroll
    for (int i = 0; i < 16; ++i) { w[i] = __expf(g[i] - m); s += w[i]; }
    float inv = 1.f / s;
    float c0 = 0, c1 = 0, c2 = 0, c3 = 0;
    #pragma unroll
    for (int i = 0; i < 16; ++i) {
        float wi = w[i] * inv;
        c0 = fmaf(wi, k0[i], c0); c1 = fmaf(wi, kp[i], c1);
        c2 = fmaf(wi, kq[i], c2); c3 = fmaf(wi, kpq[i], c3);
    }
    C[0] = c0; C[1] = c1; C[2] = c2; C[3] = c3;
}

__global__ void coeff_kernel(const float* __restrict__ sa1, const float* __restrict__ sb1, const float* __restrict__ g1,
                             const float* __restrict__ sa2, const float* __restrict__ sb2, const float* __restrict__ g2,
                             const float* __restrict__ sa3, const float* __restrict__ sb3, const float* __restrict__ g3,
                             const float* __restrict__ sa4, const float* __restrict__ sb4, const float* __restrict__ g4,
                             float* __restrict__ cf) {
    const int t = threadIdx.x;
    if (t < 15) {                 // softmax of sel_a rows
        int r = t;
        if      (r < 8)  softmax_row<9>(sa1 + r * 9,        cf + r * 9);
        else if (r < 12) softmax_row<8>(sa2 + (r - 8) * 8,  cf + 176 + (r - 8) * 8);
        else if (r < 14) softmax_row<4>(sa3 + (r - 12) * 4, cf + 256 + (r - 12) * 4);
        else             softmax_row<2>(sa4,                cf + 280);
    } else if (t >= 16 && t < 31) {   // softmax of sel_b rows
        int r = t - 16;
        if      (r < 8)  softmax_row<9>(sb1 + r * 9,        cf + 72 + r * 9);
        else if (r < 12) softmax_row<8>(sb2 + (r - 8) * 8,  cf + 208 + (r - 8) * 8);
        else if (r < 14) softmax_row<4>(sb3 + (r - 12) * 4, cf + 264 + (r - 12) * 4);
        else             softmax_row<2>(sb4,                cf + 282);
    } else if (t >= 32 && t < 47) {   // gate-logit folds
        int r = t - 32;
        if      (r < 8)  gate_fold(g1 + r * 16,        cf + 144 + r * 4);
        else if (r < 12) gate_fold(g2 + (r - 8) * 16,  cf + 240 + (r - 8) * 4);
        else if (r < 14) gate_fold(g3 + (r - 12) * 16, cf + 272 + (r - 12) * 4);
        else             gate_fold(g4,                 cf + 284);
    }
}

__global__ __launch_bounds__(THREADS, 8) void net_kernel(
        const float* __restrict__ x, const float* __restrict__ cf,
        float* __restrict__ out, int nB) {
    const long b0 = ((long)blockIdx.x * THREADS + threadIdx.x) * SPT;
    if (b0 >= nB) return;

    // ---- load 2 consecutive samples = 18 contiguous floats (72B, 8B-aligned)
    //      as 4x dwordx4 + 1x dwordx2 (nontemporal), transpose in registers. ----
    v2f v[9];
    if (b0 + 1 < nB) {
        const float* __restrict__ xp = x + b0 * 9;
        v4f r0 = __builtin_nontemporal_load((const v4f*)(xp));       // f0..f3
        v4f r1 = __builtin_nontemporal_load((const v4f*)(xp + 4));   // f4..f7
        v4f r2 = __builtin_nontemporal_load((const v4f*)(xp + 8));   // f8..f11
        v4f r3 = __builtin_nontemporal_load((const v4f*)(xp + 12));  // f12..f15
        v2f r4 = __builtin_nontemporal_load((const v2f*)(xp + 16));  // f16..f17
        // v[i] = { sample0[i], sample1[i] } = { f[i], f[9+i] }
        v[0].x = r0.x; v[0].y = r2.y;
        v[1].x = r0.y; v[1].y = r2.z;
        v[2].x = r0.z; v[2].y = r2.w;
        v[3].x = r0.w; v[3].y = r3.x;
        v[4].x = r1.x; v[4].y = r3.y;
        v[5].x = r1.y; v[5].y = r3.z;
        v[6].x = r1.z; v[6].y = r3.w;
        v[7].x = r1.w; v[7].y = r4.x;
        v[8].x = r2.x; v[8].y = r4.y;
    } else {                                   // last lone sample
        #pragma unroll
        for (int i = 0; i < 9; ++i) { float t = x[b0 * 9 + i]; v[i].x = t; v[i].y = t; }
    }

    // ---- Layer 1: 9 -> 8 (packed; coeffs = SGPR via uniform s_load) ----
    v2f h1[8];
    #pragma unroll
    for (int j = 0; j < 8; ++j) {
        v2f p = sp(0.f), q = sp(0.f);
        #pragma unroll
        for (int i = 0; i < 9; ++i) {
            p = pfma(v[i], sp(cf[     j * 9 + i]), p);
            q = pfma(v[i], sp(cf[72 + j * 9 + i]), q);
        }
        h1[j] = pfma(sp(cf[144 + j*4 + 3]), p * q,
                pfma(sp(cf[144 + j*4 + 2]), q,
                pfma(sp(cf[144 + j*4 + 1]), p, sp(cf[144 + j*4 + 0]))));
    }
    // ---- Layer 2: 8 -> 4 ----
    v2f h2[4];
    #pragma unroll
    for (int j = 0; j < 4; ++j) {
        v2f p = sp(0.f), q = sp(0.f);
        #pragma unroll
        for (int i = 0; i < 8; ++i) {
            p = pfma(h1[i], sp(cf[176 + j * 8 + i]), p);
            q = pfma(h1[i], sp(cf[208 + j * 8 + i]), q);
        }
        h2[j] = pfma(sp(cf[240 + j*4 + 3]), p * q,
                pfma(sp(cf[240 + j*4 + 2]), q,
                pfma(sp(cf[240 + j*4 + 1]), p, sp(cf[240 + j*4 + 0]))));
    }
    // ---- Layer 3: 4 -> 2 ----
    v2f h3[2];
    #pragma unroll
    for (int j = 0; j < 2; ++j) {
        v2f p = sp(0.f), q = sp(0.f);
        #pragma unroll
        for (int i = 0; i < 4; ++i) {
            p = pfma(h2[i], sp(cf[256 + j * 4 + i]), p);
            q = pfma(h2[i], sp(cf[264 + j * 4 + i]), q);
        }
        h3[j] = pfma(sp(cf[272 + j*4 + 3]), p * q,
                pfma(sp(cf[272 + j*4 + 2]), q,
                pfma(sp(cf[272 + j*4 + 1]), p, sp(cf[272 + j*4 + 0]))));
    }
    // ---- Layer 4: 2 -> 1 ----
    v2f p = pfma(h3[0], sp(cf[280]), h3[1] * sp(cf[281]));
    v2f q = pfma(h3[0], sp(cf[282]), h3[1] * sp(cf[283]));
    v2f o = pfma(sp(cf[287]), p * q,
            pfma(sp(cf[286]), q,
            pfma(sp(cf[285]), p, sp(cf[284]))));

    if (b0 + 1 < nB) {
        __builtin_nontemporal_store(o, (v2f*)(out + b0));   // dwordx2, contiguous
    } else {
        out[b0] = o.x;
    }
}

extern "C" void kernel_launch(void* const* d_in, const int* in_sizes, int n_in,
                              void* d_out, int out_size, void* d_ws, size_t ws_size,
                              hipStream_t stream) {
    const float* x   = (const float*)d_in[0];
    const float* sa1 = (const float*)d_in[1];
    const float* sb1 = (const float*)d_in[2];
    const float* g1  = (const float*)d_in[3];
    const float* sa2 = (const float*)d_in[4];
    const float* sb2 = (const float*)d_in[5];
    const float* g2  = (const float*)d_in[6];
    const float* sa3 = (const float*)d_in[7];
    const float* sb3 = (const float*)d_in[8];
    const float* g3  = (const float*)d_in[9];
    const float* sa4 = (const float*)d_in[10];
    const float* sb4 = (const float*)d_in[11];
    const float* g4  = (const float*)d_in[12];
    float* cf = (float*)d_ws;                 // 288 floats (ws poison is unconditional -> free)
    const int nB = in_sizes[0] / 9;

    coeff_kernel<<<1, 64, 0, stream>>>(sa1, sb1, g1, sa2, sb2, g2,
                                       sa3, sb3, g3, sa4, sb4, g4, cf);
    const int grid = (nB + B_PER_BLOCK - 1) / B_PER_BLOCK;
    net_kernel<<<grid, THREADS, 0, stream>>>(x, cf, (float*)d_out, nB);
}

// Round 8
// 108.086 us; speedup vs baseline: 1.0571x; 1.0571x over previous
//
#include <hip/hip_runtime.h>
#include <math.h>

// ---------------------------------------------------------------------------
// Difflogic network, collapsed form:
//   per neuron: out = c0 + c1*p + c2*q + c3*p*q,  p = A·x, q = B·x
//   A,B = softmax(sel), (c0..c3) = softmax(gate_logits) · gate-coef table
//
// R15 -> R16: EXACT REVERT to R14 (best: 106.4us).
// R15's nontemporal hints regressed 8us: x's 72B/thread spans straddle 64B
// lines shared across adjacent threads; those second touches were L2 hits,
// and 'nt' (evict-first) pushed them back to HBM. Lesson recorded.
// Budget decomposition (measured across R9-R15):
//   ~86us unconditional harness poison-fills (present with AND without d_ws)
//   + ~1.5us coeff kernel + ~13us steady net + ~5us first-dispatch warmup
//   amortization = ~106us. Staged-LDS (R13) and direct (R14) net variants
//   converge at the same time; packed math bought 2us; fusion spills or is
//   LDS-pipe-bound; NT hurts. If this reproduces ~106.4 -> roofline.
//
// ws layout (floats):
//   A1:   0 (72)   B1:  72 (72)   C1: 144 (32)
//   A2: 176 (32)   B2: 208 (32)   C2: 240 (16)
//   A3: 256 ( 8)   B3: 264 ( 8)   C3: 272 ( 8)
//   A4: 280 ( 2)   B4: 282 ( 2)   C4: 284 ( 4)   total 288 floats = 1152 B
// ---------------------------------------------------------------------------

#define THREADS 256
#define SPT 2                              // samples per thread (packed)
#define B_PER_BLOCK (THREADS * SPT)        // 512 samples

typedef float v2f __attribute__((ext_vector_type(2)));

static __device__ __forceinline__ v2f sp(float s) { v2f r; r.x = s; r.y = s; return r; }
static __device__ __forceinline__ v2f pfma(v2f a, v2f b, v2f c) {
    return __builtin_elementwise_fma(a, b, c);
}

template <int D>
__device__ __forceinline__ void softmax_row(const float* __restrict__ src,
                                            float* __restrict__ dst) {
    float e[D];
    float m = src[0];
    #pragma unroll
    for (int i = 1; i < D; ++i) m = fmaxf(m, src[i]);
    float s = 0.f;
    #pragma unroll
    for (int i = 0; i < D; ++i) { e[i] = __expf(src[i] - m); s += e[i]; }
    float inv = 1.f / s;
    #pragma unroll
    for (int i = 0; i < D; ++i) dst[i] = e[i] * inv;
}

__device__ __forceinline__ void gate_fold(const float* __restrict__ g,
                                          float* __restrict__ C) {
    const float k0[16]  = {0,0,0,0, 0,0,0,0, 1, 1, 1, 1, 1, 1, 1, 1};
    const float kp[16]  = {0,0,1,1, 0,0,1,1,-1,-1, 0, 0,-1,-1, 0, 0};
    const float kq[16]  = {0,0,0,0, 1,1,1,1,-1,-1,-1,-1, 0, 0, 0, 0};
    const float kpq[16] = {0,1,-1,0,-1,0,-2,-1, 1, 2, 0, 1, 0, 1,-1, 0};
    float w[16];
    float m = g[0];
    #pragma unroll
    for (int i = 1; i < 16; ++i) m = fmaxf(m, g[i]);
    float s = 0.f;
    #pragma unroll
    for (int i = 0; i < 16; ++i) { w[i] = __expf(g[i] - m); s += w[i]; }
    float inv = 1.f / s;
    float c0 = 0, c1 = 0, c2 = 0, c3 = 0;
    #pragma unroll
    for (int i = 0; i < 16; ++i) {
        float wi = w[i] * inv;
        c0 = fmaf(wi, k0[i], c0); c1 = fmaf(wi, kp[i], c1);
        c2 = fmaf(wi, kq[i], c2); c3 = fmaf(wi, kpq[i], c3);
    }
    C[0] = c0; C[1] = c1; C[2] = c2; C[3] = c3;
}

__global__ void coeff_kernel(const float* __restrict__ sa1, const float* __restrict__ sb1, const float* __restrict__ g1,
                             const float* __restrict__ sa2, const float* __restrict__ sb2, const float* __restrict__ g2,
                             const float* __restrict__ sa3, const float* __restrict__ sb3, const float* __restrict__ g3,
                             const float* __restrict__ sa4, const float* __restrict__ sb4, const float* __restrict__ g4,
                             float* __restrict__ cf) {
    const int t = threadIdx.x;
    if (t < 15) {                 // softmax of sel_a rows
        int r = t;
        if      (r < 8)  softmax_row<9>(sa1 + r * 9,        cf + r * 9);
        else if (r < 12) softmax_row<8>(sa2 + (r - 8) * 8,  cf + 176 + (r - 8) * 8);
        else if (r < 14) softmax_row<4>(sa3 + (r - 12) * 4, cf + 256 + (r - 12) * 4);
        else             softmax_row<2>(sa4,                cf + 280);
    } else if (t >= 16 && t < 31) {   // softmax of sel_b rows
        int r = t - 16;
        if      (r < 8)  softmax_row<9>(sb1 + r * 9,        cf + 72 + r * 9);
        else if (r < 12) softmax_row<8>(sb2 + (r - 8) * 8,  cf + 208 + (r - 8) * 8);
        else if (r < 14) softmax_row<4>(sb3 + (r - 12) * 4, cf + 264 + (r - 12) * 4);
        else             softmax_row<2>(sb4,                cf + 282);
    } else if (t >= 32 && t < 47) {   // gate-logit folds
        int r = t - 32;
        if      (r < 8)  gate_fold(g1 + r * 16,        cf + 144 + r * 4);
        else if (r < 12) gate_fold(g2 + (r - 8) * 16,  cf + 240 + (r - 8) * 4);
        else if (r < 14) gate_fold(g3 + (r - 12) * 16, cf + 272 + (r - 12) * 4);
        else             gate_fold(g4,                 cf + 284);
    }
}

__global__ __launch_bounds__(THREADS, 8) void net_kernel(
        const float* __restrict__ x, const float* __restrict__ cf,
        float* __restrict__ out, int nB) {
    const long b0 = ((long)blockIdx.x * THREADS + threadIdx.x) * SPT;
    if (b0 >= nB) return;

    // ---- load 2 consecutive samples = 18 contiguous floats, 8B-aligned:
    //      9x global_load_dwordx2; transpose to {s0[i],s1[i]} in registers
    //      (all indices compile-time -> pure register selects). ----
    v2f v[9];
    if (b0 + 1 < nB) {
        const v2f* __restrict__ xp = (const v2f*)(x + b0 * 9);
        v2f r[9];
        #pragma unroll
        for (int i = 0; i < 9; ++i) r[i] = xp[i];
        v[0].x = r[0].x; v[0].y = r[4].y;
        v[1].x = r[0].y; v[1].y = r[5].x;
        v[2].x = r[1].x; v[2].y = r[5].y;
        v[3].x = r[1].y; v[3].y = r[6].x;
        v[4].x = r[2].x; v[4].y = r[6].y;
        v[5].x = r[2].y; v[5].y = r[7].x;
        v[6].x = r[3].x; v[6].y = r[7].y;
        v[7].x = r[3].y; v[7].y = r[8].x;
        v[8].x = r[4].x; v[8].y = r[8].y;
    } else {                                   // last lone sample
        #pragma unroll
        for (int i = 0; i < 9; ++i) { float t = x[b0 * 9 + i]; v[i].x = t; v[i].y = t; }
    }

    // ---- Layer 1: 9 -> 8 (packed; coeffs = SGPR via uniform s_load) ----
    v2f h1[8];
    #pragma unroll
    for (int j = 0; j < 8; ++j) {
        v2f p = sp(0.f), q = sp(0.f);
        #pragma unroll
        for (int i = 0; i < 9; ++i) {
            p = pfma(v[i], sp(cf[     j * 9 + i]), p);
            q = pfma(v[i], sp(cf[72 + j * 9 + i]), q);
        }
        h1[j] = pfma(sp(cf[144 + j*4 + 3]), p * q,
                pfma(sp(cf[144 + j*4 + 2]), q,
                pfma(sp(cf[144 + j*4 + 1]), p, sp(cf[144 + j*4 + 0]))));
    }
    // ---- Layer 2: 8 -> 4 ----
    v2f h2[4];
    #pragma unroll
    for (int j = 0; j < 4; ++j) {
        v2f p = sp(0.f), q = sp(0.f);
        #pragma unroll
        for (int i = 0; i < 8; ++i) {
            p = pfma(h1[i], sp(cf[176 + j * 8 + i]), p);
            q = pfma(h1[i], sp(cf[208 + j * 8 + i]), q);
        }
        h2[j] = pfma(sp(cf[240 + j*4 + 3]), p * q,
                pfma(sp(cf[240 + j*4 + 2]), q,
                pfma(sp(cf[240 + j*4 + 1]), p, sp(cf[240 + j*4 + 0]))));
    }
    // ---- Layer 3: 4 -> 2 ----
    v2f h3[2];
    #pragma unroll
    for (int j = 0; j < 2; ++j) {
        v2f p = sp(0.f), q = sp(0.f);
        #pragma unroll
        for (int i = 0; i < 4; ++i) {
            p = pfma(h2[i], sp(cf[256 + j * 4 + i]), p);
            q = pfma(h2[i], sp(cf[264 + j * 4 + i]), q);
        }
        h3[j] = pfma(sp(cf[272 + j*4 + 3]), p * q,
                pfma(sp(cf[272 + j*4 + 2]), q,
                pfma(sp(cf[272 + j*4 + 1]), p, sp(cf[272 + j*4 + 0]))));
    }
    // ---- Layer 4: 2 -> 1 ----
    v2f p = pfma(h3[0], sp(cf[280]), h3[1] * sp(cf[281]));
    v2f q = pfma(h3[0], sp(cf[282]), h3[1] * sp(cf[283]));
    v2f o = pfma(sp(cf[287]), p * q,
            pfma(sp(cf[286]), q,
            pfma(sp(cf[285]), p, sp(cf[284]))));

    if (b0 + 1 < nB) {
        *(v2f*)(out + b0) = o;                 // dwordx2, wave-contiguous
    } else {
        out[b0] = o.x;
    }
}

extern "C" void kernel_launch(void* const* d_in, const int* in_sizes, int n_in,
                              void* d_out, int out_size, void* d_ws, size_t ws_size,
                              hipStream_t stream) {
    const float* x   = (const float*)d_in[0];
    const float* sa1 = (const float*)d_in[1];
    const float* sb1 = (const float*)d_in[2];
    const float* g1  = (const float*)d_in[3];
    const float* sa2 = (const float*)d_in[4];
    const float* sb2 = (const float*)d_in[5];
    const float* g2  = (const float*)d_in[6];
    const float* sa3 = (const float*)d_in[7];
    const float* sb3 = (const float*)d_in[8];
    const float* g3  = (const float*)d_in[9];
    const float* sa4 = (const float*)d_in[10];
    const float* sb4 = (const float*)d_in[11];
    const float* g4  = (const float*)d_in[12];
    float* cf = (float*)d_ws;                 // 288 floats (ws poison is unconditional -> free)
    const int nB = in_sizes[0] / 9;

    coeff_kernel<<<1, 64, 0, stream>>>(sa1, sb1, g1, sa2, sb2, g2,
                                       sa3, sb3, g3, sa4, sb4, g4, cf);
    const int grid = (nB + B_PER_BLOCK - 1) / B_PER_BLOCK;
    net_kernel<<<grid, THREADS, 0, stream>>>(x, cf, (float*)d_out, nB);
}